// Round 5
// baseline (284.239 us; speedup 1.0000x reference)
//
#include <hip/hip_runtime.h>
#include <hip/hip_cooperative_groups.h>
#include <math.h>

namespace cg = cooperative_groups;

#define NNODE 32768
#define NTHR  256

// fast guarded reciprocal (distance path only; branch boundaries are continuous)
__device__ __forceinline__ float rguard(float d) {
    float dd = (fabsf(d) < 1e-12f) ? 1e-12f : d;
    return __builtin_amdgcn_rcpf(dd);
}

// identical cell computation used by both the marking phase and the sum phase
__device__ __forceinline__ void cell_of(float px, float py, float pz,
                                        int& x0, int& y0, int& z0,
                                        float& wx, float& wy, float& wz) {
#pragma clang fp contract(off)
    float fx = (px + 1.0f) * 0.5f * 31.0f;
    float fy = (py + 1.0f) * 0.5f * 31.0f;
    float fz = (pz + 1.0f) * 0.5f * 31.0f;
    float x0f = floorf(fx), y0f = floorf(fy), z0f = floorf(fz);
    wx = fx - x0f; wy = fy - y0f; wz = fz - z0f;
    x0 = (int)fmaxf(fminf(x0f, 33.0f), -2.0f);
    y0 = (int)fmaxf(fminf(y0f, 33.0f), -2.0f);
    z0 = (int)fmaxf(fminf(z0f, 33.0f), -2.0f);
}

// block-cooperative bbox of hull 1 -> center/scale in every thread's registers.
// Cheap (V=778), so each block that needs it just recomputes it.
__device__ __forceinline__ void bbox_of(const float* __restrict__ verts, int V,
                                        float& ocx, float& ocy, float& ocz,
                                        float& osc) {
#pragma clang fp contract(off)
    const float* v1 = verts + (size_t)V * 3;  // hull 1
    float mn[3] = {1e30f, 1e30f, 1e30f};
    float mx[3] = {-1e30f, -1e30f, -1e30f};
    for (int i = threadIdx.x; i < V; i += NTHR) {
        for (int c = 0; c < 3; ++c) {
            float val = v1[i * 3 + c];
            mn[c] = fminf(mn[c], val);
            mx[c] = fmaxf(mx[c], val);
        }
    }
    for (int off = 32; off >= 1; off >>= 1) {
        for (int c = 0; c < 3; ++c) {
            mn[c] = fminf(mn[c], __shfl_down(mn[c], off));
            mx[c] = fmaxf(mx[c], __shfl_down(mx[c], off));
        }
    }
    __shared__ float smn[4][3], smx[4][3];
    int wv = threadIdx.x >> 6, lane = threadIdx.x & 63;
    if (lane == 0)
        for (int c = 0; c < 3; ++c) { smn[wv][c] = mn[c]; smx[wv][c] = mx[c]; }
    __syncthreads();
    float ext = -1e30f, cc[3];
    for (int c = 0; c < 3; ++c) {
        float lo = fminf(fminf(smn[0][c], smn[1][c]), fminf(smn[2][c], smn[3][c]));
        float hi = fmaxf(fmaxf(smx[0][c], smx[1][c]), fmaxf(smx[2][c], smx[3][c]));
        cc[c] = (lo + hi) * 0.5f;
        ext = fmaxf(ext, hi - lo);
    }
    ocx = cc[0]; ocy = cc[1]; ocz = cc[2];
    osc = (1.0f + 0.2f) * 0.5f * ext;
    __syncthreads();
}

// triangle records: a(3) b(3) c(3) inv_det det pad  (inv_det exact IEEE)
__device__ __forceinline__ void tri_records(const float* __restrict__ verts,
                                            const int* __restrict__ faces,
                                            float cx0, float cy0, float cz0, float sc,
                                            float* __restrict__ tri, int V, int F,
                                            int start, int stride) {
#pragma clang fp contract(off)
    const float* v1 = verts + (size_t)V * 3;
    for (int f = start; f < F; f += stride) {
        int i0 = faces[f * 3 + 0], i1 = faces[f * 3 + 1], i2 = faces[f * 3 + 2];
        float ax = (v1[i0 * 3 + 0] - cx0) / sc, ay = (v1[i0 * 3 + 1] - cy0) / sc,
              az = (v1[i0 * 3 + 2] - cz0) / sc;
        float bx = (v1[i1 * 3 + 0] - cx0) / sc, by = (v1[i1 * 3 + 1] - cy0) / sc,
              bz = (v1[i1 * 3 + 2] - cz0) / sc;
        float cx = (v1[i2 * 3 + 0] - cx0) / sc, cy = (v1[i2 * 3 + 1] - cy0) / sc,
              cz = (v1[i2 * 3 + 2] - cz0) / sc;
        float aby = by - ay, abz = bz - az;
        float acy = cy - ay, acz = cz - az;
        float det = aby * (-acz) + abz * acy;
        float dd = (fabsf(det) < 1e-12f) ? 1e-12f : det;
        float inv = 1.0f / dd;  // IEEE — parity test must stay bit-exact
        float* r = tri + (size_t)f * 12;
        r[0] = ax; r[1] = ay; r[2] = az;
        r[3] = bx; r[4] = by; r[5] = bz;
        r[6] = cx; r[7] = cy; r[8] = cz;
        r[9] = inv; r[10] = det; r[11] = 0.0f;
    }
}

// mark + compact the grid nodes actually read by trilinear (hull-0 points).
// Whole waves iterate together (padded bound) so ballot aggregation is safe.
__device__ __forceinline__ void mark_nodes(const float* __restrict__ verts,
                                           float cx0, float cy0, float cz0, float sc,
                                           int* __restrict__ flags, int* __restrict__ cnt,
                                           int* __restrict__ list, int V,
                                           int start, int stride) {
    const int lane = threadIdx.x & 63;
    const int Vpad = (V + 63) & ~63;
    for (int i = start; i < Vpad; i += stride) {
        bool havept = i < V;
        int x0 = 0, y0 = 0, z0 = 0;
        float wx, wy, wz;
        if (havept) {
#pragma clang fp contract(off)
            float px = (verts[i * 3 + 0] - cx0) / sc;  // hull-0 vertex
            float py = (verts[i * 3 + 1] - cy0) / sc;
            float pz = (verts[i * 3 + 2] - cz0) / sc;
            cell_of(px, py, pz, x0, y0, z0, wx, wy, wz);
        }
        for (int k = 0; k < 8; ++k) {
            int zi = z0 + ((k >> 2) & 1), yi = y0 + ((k >> 1) & 1), xi = x0 + (k & 1);
            bool valid = havept && (unsigned)zi < 32u && (unsigned)yi < 32u &&
                         (unsigned)xi < 32u;
            int node = (zi * 32 + yi) * 32 + xi;
            bool newly = false;
            if (valid) newly = (atomicExch(&flags[node], 1) == 0);
            unsigned long long m = __ballot(newly);
            if (m) {  // wave-aggregated append: ONE cnt atomic per wave per corner
                int leader = __ffsll((long long)m) - 1;
                int base = 0;
                if (lane == leader) base = atomicAdd(cnt, __popcll(m));
                base = __shfl(base, leader);
                if (newly)
                    list[base + __popcll(m & ((1ull << lane) - 1ull))] = node;
            }
        }
    }
}

// per-(node, 64-triangle chunk) distance + parity
__device__ __forceinline__ void chunks_phase(const float* __restrict__ tri,
                                             const int* __restrict__ list, int n,
                                             unsigned int* __restrict__ d2b,
                                             int* __restrict__ hits, int F, int nch,
                                             unsigned long long magic, int wid, int nw) {
    const int lane = threadIdx.x & 63;
    const int total = n * nch;
    for (int w = wid; w < total; w += nw) {
        const int q = (int)(((unsigned long long)(unsigned int)w * magic) >> 40);
        const int ck = w - q * nch;
        const int node = list[q];
        const int xi = node & 31, yi = (node >> 5) & 31, zi = node >> 10;
        float px, py, pz;
        {
#pragma clang fp contract(off)
            px = (float)((double)xi * (2.0 / 31.0) - 1.0);
            py = (float)((double)yi * (2.0 / 31.0) - 1.0);
            pz = (float)((double)zi * (2.0 / 31.0) - 1.0);
        }
        float mind2 = 1e30f;
        int h = 0;
        const int f = ck * 64 + lane;
        if (f < F) {
            const float* r = tri + (size_t)f * 12;
            float ax = r[0], ay = r[1], az = r[2];
            float bx = r[3], by = r[4], bz = r[5];
            float cx = r[6], cy = r[7], cz = r[8];
            float inv = r[9], det = r[10];
            float abx = bx - ax, aby = by - ay, abz = bz - az;
            float acx = cx - ax, acy = cy - ay, acz = cz - az;
            float apx = px - ax, apy = py - ay, apz = pz - az;
            // distance path: contraction + fast rcp (continuous at branch bounds)
            {
#pragma clang fp contract(fast)
                float d1 = abx * apx + aby * apy + abz * apz;
                float d2 = acx * apx + acy * apy + acz * apz;
                float bpx = px - bx, bpy = py - by, bpz = pz - bz;
                float d3 = abx * bpx + aby * bpy + abz * bpz;
                float d4 = acx * bpx + acy * bpy + acz * bpz;
                float cpx = px - cx, cpy = py - cy, cpz = pz - cz;
                float d5 = abx * cpx + aby * cpy + abz * cpz;
                float d6 = acx * cpx + acy * cpy + acz * cpz;
                float vc = d1 * d4 - d3 * d2;
                float vb = d5 * d2 - d1 * d6;
                float va = d3 * d6 - d5 * d4;
                float denom = va + vb + vc;
                float rd = rguard(denom);
                float v_in = vb * rd, w_in = vc * rd;
                float rx = ax + abx * v_in + acx * w_in;
                float ry = ay + aby * v_in + acy * w_in;
                float rz = az + abz * v_in + acz * w_in;
                if (va <= 0.0f && (d4 - d3) >= 0.0f && (d5 - d6) >= 0.0f) {
                    float w2 = (d4 - d3) * rguard((d4 - d3) + (d5 - d6));
                    rx = bx + (cx - bx) * w2; ry = by + (cy - by) * w2;
                    rz = bz + (cz - bz) * w2;
                }
                if (vb <= 0.0f && d2 >= 0.0f && d6 <= 0.0f) {
                    float w2 = d2 * rguard(d2 - d6);
                    rx = ax + acx * w2; ry = ay + acy * w2; rz = az + acz * w2;
                }
                if (vc <= 0.0f && d1 >= 0.0f && d3 <= 0.0f) {
                    float w2 = d1 * rguard(d1 - d3);
                    rx = ax + abx * w2; ry = ay + aby * w2; rz = az + abz * w2;
                }
                if (d6 >= 0.0f && d5 <= d6) { rx = cx; ry = cy; rz = cz; }
                if (d3 >= 0.0f && d4 <= d3) { rx = bx; ry = by; rz = bz; }
                if (d1 <= 0.0f && d2 <= 0.0f) { rx = ax; ry = ay; rz = az; }
                float ddx = px - rx, ddy = py - ry, ddz = pz - rz;
                mind2 = ddx * ddx + ddy * ddy + ddz * ddz;
            }
            // parity path: bit-exact (a flip is a large, discontinuous loss change)
            {
#pragma clang fp contract(off)
                float u = (apy * (-acz) + apz * acy) * inv;
                float qx = apy * abz - apz * aby;
                float qy = apz * abx - apx * abz;
                float qz = apx * aby - apy * abx;
                float v = qx * inv;
                float tt = (acx * qx + acy * qy + acz * qz) * inv;
                h = (fabsf(det) > 1e-9f && u >= 0.0f && u <= 1.0f && v >= 0.0f &&
                     (u + v) <= 1.0f && tt > 0.0f) ? 1 : 0;
            }
        }
        for (int off = 32; off >= 1; off >>= 1) {
            mind2 = fminf(mind2, __shfl_xor(mind2, off));
            h += __shfl_xor(h, off);
        }
        if (lane == 0) {
            atomicMin(d2b + node, __float_as_uint(mind2));
            atomicAdd(hits + node, h);
        }
    }
}

// trilinear sample at hull-0 vertices + block reduce (one 256-thread block)
__device__ __forceinline__ void sum_phase(const float* __restrict__ verts,
                                          float cx, float cy, float cz, float sc,
                                          const unsigned int* __restrict__ d2b,
                                          const int* __restrict__ hits,
                                          float* __restrict__ out, int V) {
#pragma clang fp contract(off)
    __shared__ float sm[NTHR];
    const int tid = threadIdx.x;
    float val = 0.0f;
    for (int i = tid; i < V; i += NTHR) {
        float px = (verts[i * 3 + 0] - cx) / sc;
        float py = (verts[i * 3 + 1] - cy) / sc;
        float pz = (verts[i * 3 + 2] - cz) / sc;
        int x0, y0, z0; float wx, wy, wz;
        cell_of(px, py, pz, x0, y0, z0, wx, wy, wz);
        auto corner = [&](int zi, int yi, int xi, float w) -> float {
#pragma clang fp contract(off)
            bool valid = (zi >= 0) && (zi <= 31) && (yi >= 0) && (yi <= 31) &&
                         (xi >= 0) && (xi <= 31);
            int zc = min(max(zi, 0), 31);
            int yc = min(max(yi, 0), 31);
            int xc = min(max(xi, 0), 31);
            int idx = (zc * 32 + yc) * 32 + xc;
            float vv = (hits[idx] & 1) ? sqrtf(fmaxf(__uint_as_float(d2b[idx]), 0.0f))
                                       : 0.0f;
            return valid ? vv * w : 0.0f;
        };
        val += corner(z0, y0, x0, (1.0f - wz) * (1.0f - wy) * (1.0f - wx))
             + corner(z0, y0, x0 + 1, (1.0f - wz) * (1.0f - wy) * wx)
             + corner(z0, y0 + 1, x0, (1.0f - wz) * wy * (1.0f - wx))
             + corner(z0, y0 + 1, x0 + 1, (1.0f - wz) * wy * wx)
             + corner(z0 + 1, y0, x0, wz * (1.0f - wy) * (1.0f - wx))
             + corner(z0 + 1, y0, x0 + 1, wz * (1.0f - wy) * wx)
             + corner(z0 + 1, y0 + 1, x0, wz * wy * (1.0f - wx))
             + corner(z0 + 1, y0 + 1, x0 + 1, wz * wy * wx);
    }
    sm[tid] = val;
    __syncthreads();
    for (int s = NTHR / 2; s >= 1; s >>= 1) {
        if (tid < s) sm[tid] += sm[tid + s];
        __syncthreads();
    }
    if (tid == 0) out[0] = sm[0] * 0.25f;  // / H^2, H=2
}

// =================== fused cooperative kernel (grid-size agnostic) ===================
__global__ void __launch_bounds__(NTHR, 4) k_all(
        const float* __restrict__ verts, const int* __restrict__ faces,
        float* __restrict__ tri, unsigned int* __restrict__ d2b,
        int* __restrict__ hits, int* __restrict__ flags, int* __restrict__ cnt,
        int* __restrict__ list, float* __restrict__ out,
        int V, int F, int nch, unsigned long long magic) {
    cg::grid_group grid = cg::this_grid();
    const int tid = threadIdx.x;
    const int nthr_total = (int)gridDim.x * NTHR;
    const int gid = (int)blockIdx.x * NTHR + tid;

    // phase 0: clear state; every block computes bbox locally (no cross-block dep)
    for (int i = gid; i < NNODE; i += nthr_total) {
        d2b[i] = 0xFFFFFFFFu; hits[i] = 0; flags[i] = 0;
    }
    if (gid == 0) cnt[0] = 0;
    float cx0, cy0, cz0, sc;
    bbox_of(verts, V, cx0, cy0, cz0, sc);
    grid.sync();

    // phase 1: triangle records + mark/compact active nodes (grid-parallel)
    tri_records(verts, faces, cx0, cy0, cz0, sc, tri, V, F, gid, nthr_total);
    mark_nodes(verts, cx0, cy0, cz0, sc, flags, cnt, list, V, gid, nthr_total);
    grid.sync();

    // phase 2: distance + parity over (active node, triangle-chunk) wave items
    chunks_phase(tri, list, cnt[0], d2b, hits, F, nch, magic, gid >> 6,
                 nthr_total >> 6);
    grid.sync();

    // phase 3: trilinear gather + reduce on block 0
    if (blockIdx.x == 0)
        sum_phase(verts, cx0, cy0, cz0, sc, d2b, hits, out, V);
}

// =================== fallback multi-kernel path (round-3 structure) ===================
__global__ void k_init(unsigned int* __restrict__ d2b, int* __restrict__ hits,
                       int* __restrict__ flags, int* __restrict__ cnt) {
    int t = blockIdx.x * NTHR + threadIdx.x;
    if (t < NNODE) { d2b[t] = 0xFFFFFFFFu; hits[t] = 0; flags[t] = 0; }
    if (t == 0) cnt[0] = 0;
}

__global__ void k_setup(const float* __restrict__ verts, const int* __restrict__ faces,
                        float* __restrict__ tri, int* __restrict__ flags,
                        int* __restrict__ cnt, int* __restrict__ list, int V, int F) {
    float cx0, cy0, cz0, sc;
    bbox_of(verts, V, cx0, cy0, cz0, sc);
    tri_records(verts, faces, cx0, cy0, cz0, sc, tri, V, F, threadIdx.x, NTHR);
    mark_nodes(verts, cx0, cy0, cz0, sc, flags, cnt, list, V, threadIdx.x, NTHR);
}

__global__ void __launch_bounds__(NTHR) k_main(const float* __restrict__ tri,
                                               const int* __restrict__ list,
                                               const int* __restrict__ cnt,
                                               unsigned int* __restrict__ d2b,
                                               int* __restrict__ hits, int F, int nch,
                                               unsigned long long magic) {
    chunks_phase(tri, list, cnt[0], d2b, hits, F, nch, magic,
                 (int)blockIdx.x * 4 + (threadIdx.x >> 6), (int)gridDim.x * 4);
}

__global__ void k_sum(const float* __restrict__ verts,
                      const unsigned int* __restrict__ d2b, const int* __restrict__ hits,
                      float* __restrict__ out, int V) {
    float cx0, cy0, cz0, sc;
    bbox_of(verts, V, cx0, cy0, cz0, sc);
    sum_phase(verts, cx0, cy0, cz0, sc, d2b, hits, out, V);
}

extern "C" void kernel_launch(void* const* d_in, const int* in_sizes, int n_in,
                              void* d_out, int out_size, void* d_ws, size_t ws_size,
                              hipStream_t stream) {
    const float* verts = (const float*)d_in[0];
    const int* faces = (const int*)d_in[1];
    float* out = (float*)d_out;
    float* ws = (float*)d_ws;

    int V = in_sizes[0] / 6;  // 2 hulls x 3 comps
    int F = in_sizes[1] / 3;

    float* tri = ws;                                   // 12*F floats
    unsigned int* d2b = (unsigned int*)(tri + 12 * (size_t)F);
    int* hits = (int*)(d2b + NNODE);
    int* flags = hits + NNODE;
    int* cnt = flags + NNODE;
    int* list = cnt + 1;                               // up to 8*V entries

    int nch = (F + 63) / 64;
    unsigned long long magic =
        ((1ULL << 40) + (unsigned long long)nch - 1) / (unsigned long long)nch;

    // Size the cooperative grid to what the runtime will actually accept.
    // (Host-side queries: capture-safe, deterministic.)
    int dev = 0;
    (void)hipGetDevice(&dev);
    int cus = 0;
    (void)hipDeviceGetAttribute(&cus, hipDeviceAttributeMultiprocessorCount, dev);
    int bpc = 0;
    hipError_t qe = hipOccupancyMaxActiveBlocksPerMultiprocessor(
        &bpc, (const void*)k_all, NTHR, 0);
    long long nblk = (qe == hipSuccess && cus > 0) ? (long long)bpc * cus : 0;
    if (nblk > 1024) nblk = 1024;

    if (nblk >= 128) {  // need nblk*NTHR >= NNODE and decent phase-2 occupancy
        void* args[] = {(void*)&verts, (void*)&faces, (void*)&tri, (void*)&d2b,
                        (void*)&hits,  (void*)&flags, (void*)&cnt, (void*)&list,
                        (void*)&out,   (void*)&V,     (void*)&F,   (void*)&nch,
                        (void*)&magic};
        hipLaunchCooperativeKernel((const void*)k_all, dim3((unsigned)nblk),
                                   dim3(NTHR), args, 0, stream);
    } else {
        k_init<<<NNODE / NTHR, NTHR, 0, stream>>>(d2b, hits, flags, cnt);
        k_setup<<<1, NTHR, 0, stream>>>(verts, faces, tri, flags, cnt, list, V, F);
        k_main<<<2048, NTHR, 0, stream>>>(tri, list, cnt, d2b, hits, F, nch, magic);
        k_sum<<<1, NTHR, 0, stream>>>(verts, d2b, hits, out, V);
    }
}

// Round 7
// 64.466 us; speedup vs baseline: 4.4091x; 4.4091x over previous
//
#include <hip/hip_runtime.h>
#include <math.h>

#define NNODE 32768
#define NTHR  256

// fast guarded reciprocal (distance path only; branch boundaries are continuous)
__device__ __forceinline__ float rguard(float d) {
    float dd = (fabsf(d) < 1e-12f) ? 1e-12f : d;
    return __builtin_amdgcn_rcpf(dd);
}

// identical cell computation used by both the marking phase and the sum phase
__device__ __forceinline__ void cell_of(float px, float py, float pz,
                                        int& x0, int& y0, int& z0,
                                        float& wx, float& wy, float& wz) {
#pragma clang fp contract(off)
    float fx = (px + 1.0f) * 0.5f * 31.0f;
    float fy = (py + 1.0f) * 0.5f * 31.0f;
    float fz = (pz + 1.0f) * 0.5f * 31.0f;
    float x0f = floorf(fx), y0f = floorf(fy), z0f = floorf(fz);
    wx = fx - x0f; wy = fy - y0f; wz = fz - z0f;
    x0 = (int)fmaxf(fminf(x0f, 33.0f), -2.0f);
    y0 = (int)fmaxf(fminf(y0f, 33.0f), -2.0f);
    z0 = (int)fmaxf(fminf(z0f, 33.0f), -2.0f);
}

// block-cooperative bbox of hull 1 -> center/scale in every thread's registers.
// Cheap (V~778), so every block that needs it just recomputes it.
__device__ __forceinline__ void bbox_of(const float* __restrict__ verts, int V,
                                        float& ocx, float& ocy, float& ocz,
                                        float& osc) {
#pragma clang fp contract(off)
    const float* v1 = verts + (size_t)V * 3;  // hull 1
    float mn[3] = {1e30f, 1e30f, 1e30f};
    float mx[3] = {-1e30f, -1e30f, -1e30f};
    for (int i = threadIdx.x; i < V; i += NTHR) {
        for (int c = 0; c < 3; ++c) {
            float val = v1[i * 3 + c];
            mn[c] = fminf(mn[c], val);
            mx[c] = fmaxf(mx[c], val);
        }
    }
    for (int off = 32; off >= 1; off >>= 1) {
        for (int c = 0; c < 3; ++c) {
            mn[c] = fminf(mn[c], __shfl_down(mn[c], off));
            mx[c] = fmaxf(mx[c], __shfl_down(mx[c], off));
        }
    }
    __shared__ float smn[4][3], smx[4][3];
    int wv = threadIdx.x >> 6, lane = threadIdx.x & 63;
    if (lane == 0)
        for (int c = 0; c < 3; ++c) { smn[wv][c] = mn[c]; smx[wv][c] = mx[c]; }
    __syncthreads();
    float ext = -1e30f, cc[3];
    for (int c = 0; c < 3; ++c) {
        float lo = fminf(fminf(smn[0][c], smn[1][c]), fminf(smn[2][c], smn[3][c]));
        float hi = fmaxf(fmaxf(smx[0][c], smx[1][c]), fmaxf(smx[2][c], smx[3][c]));
        cc[c] = (lo + hi) * 0.5f;
        ext = fmaxf(ext, hi - lo);
    }
    ocx = cc[0]; ocy = cc[1]; ocz = cc[2];
    osc = (1.0f + 0.2f) * 0.5f * ext;
    __syncthreads();
}

// ---- init: d2b=+inf bits, hits=0, flags=0, cnt=0 ----
__global__ void k_init(unsigned int* __restrict__ d2b, int* __restrict__ hits,
                       int* __restrict__ flags, int* __restrict__ cnt) {
    int t = blockIdx.x * NTHR + threadIdx.x;
    if (t < NNODE) { d2b[t] = 0xFFFFFFFFu; hits[t] = 0; flags[t] = 0; }
    if (t == 0) cnt[0] = 0;
}

// ---- setup (MULTI-BLOCK): triangle records + mark/compact active nodes ----
__global__ void k_setup(const float* __restrict__ verts, const int* __restrict__ faces,
                        float* __restrict__ tri, int* __restrict__ flags,
                        int* __restrict__ cnt, int* __restrict__ list, int V, int F) {
    float cx0, cy0, cz0, sc;
    bbox_of(verts, V, cx0, cy0, cz0, sc);
    const int gid = (int)blockIdx.x * NTHR + threadIdx.x;
    const int stride = (int)gridDim.x * NTHR;
    const int lane = threadIdx.x & 63;

    // triangle records: a(3) b(3) c(3) inv_det det pad  (inv_det exact IEEE)
    {
#pragma clang fp contract(off)
        const float* v1 = verts + (size_t)V * 3;
        for (int f = gid; f < F; f += stride) {
            int i0 = faces[f * 3 + 0], i1 = faces[f * 3 + 1], i2 = faces[f * 3 + 2];
            float ax = (v1[i0 * 3 + 0] - cx0) / sc, ay = (v1[i0 * 3 + 1] - cy0) / sc,
                  az = (v1[i0 * 3 + 2] - cz0) / sc;
            float bx = (v1[i1 * 3 + 0] - cx0) / sc, by = (v1[i1 * 3 + 1] - cy0) / sc,
                  bz = (v1[i1 * 3 + 2] - cz0) / sc;
            float cx = (v1[i2 * 3 + 0] - cx0) / sc, cy = (v1[i2 * 3 + 1] - cy0) / sc,
                  cz = (v1[i2 * 3 + 2] - cz0) / sc;
            float aby = by - ay, abz = bz - az;
            float acy = cy - ay, acz = cz - az;
            float det = aby * (-acz) + abz * acy;
            float dd = (fabsf(det) < 1e-12f) ? 1e-12f : det;
            float inv = 1.0f / dd;  // IEEE — parity test must stay bit-exact
            float* r = tri + (size_t)f * 12;
            r[0] = ax; r[1] = ay; r[2] = az;
            r[3] = bx; r[4] = by; r[5] = bz;
            r[6] = cx; r[7] = cy; r[8] = cz;
            r[9] = inv; r[10] = det; r[11] = 0.0f;
        }
    }

    // mark + compact grid nodes actually read by trilinear (hull-0 points).
    // Vpad is a multiple of 64 and waves are 64-aligned in gid, so the loop
    // condition is wave-uniform and the ballot aggregation is safe.
    {
        const int Vpad = (V + 63) & ~63;
        for (int i = gid; i < Vpad; i += stride) {
            bool havept = i < V;
            int x0 = 0, y0 = 0, z0 = 0;
            float wx, wy, wz;
            if (havept) {
#pragma clang fp contract(off)
                float px = (verts[i * 3 + 0] - cx0) / sc;  // hull-0 vertex
                float py = (verts[i * 3 + 1] - cy0) / sc;
                float pz = (verts[i * 3 + 2] - cz0) / sc;
                cell_of(px, py, pz, x0, y0, z0, wx, wy, wz);
            }
            for (int k = 0; k < 8; ++k) {
                int zi = z0 + ((k >> 2) & 1), yi = y0 + ((k >> 1) & 1),
                    xi = x0 + (k & 1);
                bool valid = havept && (unsigned)zi < 32u && (unsigned)yi < 32u &&
                             (unsigned)xi < 32u;
                int node = (zi * 32 + yi) * 32 + xi;
                bool newly = false;
                if (valid) newly = (atomicExch(&flags[node], 1) == 0);
                unsigned long long m = __ballot(newly);
                if (m) {  // wave-aggregated append: ONE cnt atomic per wave per corner
                    int leader = __ffsll((long long)m) - 1;
                    int base = 0;
                    if (lane == leader) base = atomicAdd(cnt, __popcll(m));
                    base = __shfl(base, leader);
                    if (newly)
                        list[base + __popcll(m & ((1ull << lane) - 1ull))] = node;
                }
            }
        }
    }
}

// ---- main: one wave per (active node, 64-triangle chunk), persistent grid ----
__global__ void __launch_bounds__(NTHR) k_main(const float* __restrict__ tri,
                                               const int* __restrict__ list,
                                               const int* __restrict__ cnt,
                                               unsigned int* __restrict__ d2b,
                                               int* __restrict__ hits, int F, int nch,
                                               unsigned long long magic) {
    const int lane = threadIdx.x & 63;
    const int wid = (int)blockIdx.x * 4 + (threadIdx.x >> 6);
    const int nw = (int)gridDim.x * 4;
    const int n = cnt[0];
    const int total = n * nch;
    for (int w = wid; w < total; w += nw) {
        const int q = (int)(((unsigned long long)(unsigned int)w * magic) >> 40);
        const int ck = w - q * nch;
        const int node = list[q];
        const int xi = node & 31, yi = (node >> 5) & 31, zi = node >> 10;
        float px, py, pz;
        {
#pragma clang fp contract(off)
            px = (float)((double)xi * (2.0 / 31.0) - 1.0);
            py = (float)((double)yi * (2.0 / 31.0) - 1.0);
            pz = (float)((double)zi * (2.0 / 31.0) - 1.0);
        }
        float mind2 = 1e30f;
        int h = 0;
        const int f = ck * 64 + lane;
        if (f < F) {
            const float* r = tri + (size_t)f * 12;
            float ax = r[0], ay = r[1], az = r[2];
            float bx = r[3], by = r[4], bz = r[5];
            float cx = r[6], cy = r[7], cz = r[8];
            float inv = r[9], det = r[10];
            float abx = bx - ax, aby = by - ay, abz = bz - az;
            float acx = cx - ax, acy = cy - ay, acz = cz - az;
            float apx = px - ax, apy = py - ay, apz = pz - az;
            // distance path: contraction + fast rcp (continuous at branch bounds)
            {
#pragma clang fp contract(fast)
                float d1 = abx * apx + aby * apy + abz * apz;
                float d2 = acx * apx + acy * apy + acz * apz;
                float bpx = px - bx, bpy = py - by, bpz = pz - bz;
                float d3 = abx * bpx + aby * bpy + abz * bpz;
                float d4 = acx * bpx + acy * bpy + acz * bpz;
                float cpx = px - cx, cpy = py - cy, cpz = pz - cz;
                float d5 = abx * cpx + aby * cpy + abz * cpz;
                float d6 = acx * cpx + acy * cpy + acz * cpz;
                float vc = d1 * d4 - d3 * d2;
                float vb = d5 * d2 - d1 * d6;
                float va = d3 * d6 - d5 * d4;
                float denom = va + vb + vc;
                float rd = rguard(denom);
                float v_in = vb * rd, w_in = vc * rd;
                float rx = ax + abx * v_in + acx * w_in;
                float ry = ay + aby * v_in + acy * w_in;
                float rz = az + abz * v_in + acz * w_in;
                if (va <= 0.0f && (d4 - d3) >= 0.0f && (d5 - d6) >= 0.0f) {
                    float w2 = (d4 - d3) * rguard((d4 - d3) + (d5 - d6));
                    rx = bx + (cx - bx) * w2; ry = by + (cy - by) * w2;
                    rz = bz + (cz - bz) * w2;
                }
                if (vb <= 0.0f && d2 >= 0.0f && d6 <= 0.0f) {
                    float w2 = d2 * rguard(d2 - d6);
                    rx = ax + acx * w2; ry = ay + acy * w2; rz = az + acz * w2;
                }
                if (vc <= 0.0f && d1 >= 0.0f && d3 <= 0.0f) {
                    float w2 = d1 * rguard(d1 - d3);
                    rx = ax + abx * w2; ry = ay + aby * w2; rz = az + abz * w2;
                }
                if (d6 >= 0.0f && d5 <= d6) { rx = cx; ry = cy; rz = cz; }
                if (d3 >= 0.0f && d4 <= d3) { rx = bx; ry = by; rz = bz; }
                if (d1 <= 0.0f && d2 <= 0.0f) { rx = ax; ry = ay; rz = az; }
                float ddx = px - rx, ddy = py - ry, ddz = pz - rz;
                mind2 = ddx * ddx + ddy * ddy + ddz * ddz;
            }
            // parity path: bit-exact (a flip is a large, discontinuous loss change)
            {
#pragma clang fp contract(off)
                float u = (apy * (-acz) + apz * acy) * inv;
                float qx = apy * abz - apz * aby;
                float qy = apz * abx - apx * abz;
                float qz = apx * aby - apy * abx;
                float v = qx * inv;
                float tt = (acx * qx + acy * qy + acz * qz) * inv;
                h = (fabsf(det) > 1e-9f && u >= 0.0f && u <= 1.0f && v >= 0.0f &&
                     (u + v) <= 1.0f && tt > 0.0f) ? 1 : 0;
            }
        }
        for (int off = 32; off >= 1; off >>= 1) {
            mind2 = fminf(mind2, __shfl_xor(mind2, off));
            h += __shfl_xor(h, off);
        }
        if (lane == 0) {
            atomicMin(d2b + node, __float_as_uint(mind2));
            atomicAdd(hits + node, h);
        }
    }
}

// ---- trilinear sample at hull-0 vertices + reduce (one 256-thread block) ----
__global__ void k_sum(const float* __restrict__ verts,
                      const unsigned int* __restrict__ d2b, const int* __restrict__ hits,
                      float* __restrict__ out, int V) {
    float cx, cy, cz, sc;
    bbox_of(verts, V, cx, cy, cz, sc);
    {
#pragma clang fp contract(off)
        __shared__ float sm[NTHR];
        const int tid = threadIdx.x;
        float val = 0.0f;
        for (int i = tid; i < V; i += NTHR) {
            float px = (verts[i * 3 + 0] - cx) / sc;
            float py = (verts[i * 3 + 1] - cy) / sc;
            float pz = (verts[i * 3 + 2] - cz) / sc;
            int x0, y0, z0; float wx, wy, wz;
            cell_of(px, py, pz, x0, y0, z0, wx, wy, wz);
            auto corner = [&](int zi, int yi, int xi, float w) -> float {
#pragma clang fp contract(off)
                bool valid = (zi >= 0) && (zi <= 31) && (yi >= 0) && (yi <= 31) &&
                             (xi >= 0) && (xi <= 31);
                int zc = min(max(zi, 0), 31);
                int yc = min(max(yi, 0), 31);
                int xc = min(max(xi, 0), 31);
                int idx = (zc * 32 + yc) * 32 + xc;
                float vv = (hits[idx] & 1)
                               ? sqrtf(fmaxf(__uint_as_float(d2b[idx]), 0.0f))
                               : 0.0f;
                return valid ? vv * w : 0.0f;
            };
            val += corner(z0, y0, x0, (1.0f - wz) * (1.0f - wy) * (1.0f - wx))
                 + corner(z0, y0, x0 + 1, (1.0f - wz) * (1.0f - wy) * wx)
                 + corner(z0, y0 + 1, x0, (1.0f - wz) * wy * (1.0f - wx))
                 + corner(z0, y0 + 1, x0 + 1, (1.0f - wz) * wy * wx)
                 + corner(z0 + 1, y0, x0, wz * (1.0f - wy) * (1.0f - wx))
                 + corner(z0 + 1, y0, x0 + 1, wz * (1.0f - wy) * wx)
                 + corner(z0 + 1, y0 + 1, x0, wz * wy * (1.0f - wx))
                 + corner(z0 + 1, y0 + 1, x0 + 1, wz * wy * wx);
        }
        sm[tid] = val;
        __syncthreads();
        for (int s = NTHR / 2; s >= 1; s >>= 1) {
            if (tid < s) sm[tid] += sm[tid + s];
            __syncthreads();
        }
        if (tid == 0) out[0] = sm[0] * 0.25f;  // / H^2, H=2
    }
}

extern "C" void kernel_launch(void* const* d_in, const int* in_sizes, int n_in,
                              void* d_out, int out_size, void* d_ws, size_t ws_size,
                              hipStream_t stream) {
    const float* verts = (const float*)d_in[0];
    const int* faces = (const int*)d_in[1];
    float* out = (float*)d_out;
    float* ws = (float*)d_ws;

    int V = in_sizes[0] / 6;  // 2 hulls x 3 comps
    int F = in_sizes[1] / 3;

    float* tri = ws;                                   // 12*F floats
    unsigned int* d2b = (unsigned int*)(tri + 12 * (size_t)F);
    int* hits = (int*)(d2b + NNODE);
    int* flags = hits + NNODE;
    int* cnt = flags + NNODE;
    int* list = cnt + 1;                               // up to 8*V entries

    int nch = (F + 63) / 64;
    unsigned long long magic =
        ((1ULL << 40) + (unsigned long long)nch - 1) / (unsigned long long)nch;

    k_init<<<NNODE / NTHR, NTHR, 0, stream>>>(d2b, hits, flags, cnt);
    k_setup<<<32, NTHR, 0, stream>>>(verts, faces, tri, flags, cnt, list, V, F);
    k_main<<<2048, NTHR, 0, stream>>>(tri, list, cnt, d2b, hits, F, nch, magic);
    k_sum<<<1, NTHR, 0, stream>>>(verts, d2b, hits, out, V);
}